// Round 1
// baseline (77.222 us; speedup 1.0000x reference)
//
#include <hip/hip_runtime.h>

// Problem constants (B=8, C=512, T=8192, RATIO=2, K=12)
#define T_LEN 8192
#define C_N   512
#define M_MAX (2 * T_LEN - 1)      // 16383, last valid upsampled index
#define TCHUNK 2048                // outputs per block
#define NCHUNK (T_LEN / TCHUNK)    // 4
#define BLOCK  256
#define OPT    8                   // outputs per thread
#define SX_LEN 2068                // sx[j] = x[clamp(n0 - 8 + j)]

__global__ void act1d_fused(const float* __restrict__ x,
                            const float* __restrict__ alpha,
                            const float* __restrict__ wup_g,
                            const float* __restrict__ wdn_g,
                            float* __restrict__ out)
{
    __shared__ __align__(16) float sx[SX_LEN];

    const int bx    = blockIdx.x;
    const int chunk = bx & (NCHUNK - 1);
    const int bc    = bx >> 2;              // row index b*C + c
    const int c     = bc & (C_N - 1);
    const int tid   = threadIdx.x;
    const int n0    = chunk * TCHUNK;

    const float* __restrict__ xrow = x   + (size_t)bc * T_LEN;
    float*       __restrict__ orow = out + (size_t)bc * T_LEN;

    // ---- Phase 1: stage x window [n0-8, n0+2059] (edge-clamped) into LDS ----
    for (int v = tid; v < SX_LEN / 4; v += BLOCK) {
        const int g = n0 - 8 + 4 * v;
        float4 val;
        if (g >= 0 && g + 3 < T_LEN) {
            val = *reinterpret_cast<const float4*>(xrow + g);
        } else {
            val.x = xrow[min(max(g + 0, 0), T_LEN - 1)];
            val.y = xrow[min(max(g + 1, 0), T_LEN - 1)];
            val.z = xrow[min(max(g + 2, 0), T_LEN - 1)];
            val.w = xrow[min(max(g + 3, 0), T_LEN - 1)];
        }
        *reinterpret_cast<float4*>(sx + 4 * v) = val;
    }
    __syncthreads();

    // ---- uniform per-thread constants ----
    float wup[12], wdn[12];
#pragma unroll
    for (int i = 0; i < 12; ++i) { wup[i] = wup_g[i]; wdn[i] = wdn_g[i]; }

    const float a     = __expf(alpha[c]);
    const float inv_a = 1.0f / (a + 1e-9f);

    const int dn = tid * OPT;               // thread's first output within chunk
    const int N  = n0 + dn;                 // global first output index

    // ---- Phase 2: LDS -> registers (6x ds_read_b128) ----
    float xr[24];
#pragma unroll
    for (int w = 0; w < 6; ++w) {
        const float4 t4 = *reinterpret_cast<const float4*>(sx + dn + 4 * w);
        xr[4 * w + 0] = t4.x;
        xr[4 * w + 1] = t4.y;
        xr[4 * w + 2] = t4.z;
        xr[4 * w + 3] = t4.w;
    }

    // ---- Phase 3: upsample, y[m] for m = 2N-5+q, q=0..25, in registers ----
    // xr[u] = sx[dn+u] = x[clamp(n0-8+dn+u)] = xp[n0-3+dn+u]  (xp[i]=x[clamp(i-5)])
    // yv[q] = 2 * sum_t wup[2t + (q&1)] * xr[(q>>1) + 8 - t]
    float yv[26];
#pragma unroll
    for (int q = 0; q < 26; ++q) {
        const int h = q >> 1;
        float acc = 0.0f;
#pragma unroll
        for (int t = 0; t < 6; ++t)
            acc = fmaf(wup[2 * t + (q & 1)], xr[h + 8 - t], acc);
        yv[q] = 2.0f * acc;
    }

    // ---- boundary fixup (only first thread of chunk 0 / last of chunk 3) ----
    const int m0g = 2 * N - 5;
    if (m0g < 0 || m0g + 25 > M_MAX) {
#pragma unroll
        for (int q = 0; q < 26; ++q) {
            const int m = m0g + q;
            if (m < 0 || m > M_MAX) {
                const int mc  = (m < 0) ? 0 : M_MAX;
                const int i0c = mc >> 1;
                const int par = mc & 1;
                float acc = 0.0f;
#pragma unroll
                for (int t = 0; t < 6; ++t)
                    acc = fmaf(wup[2 * t + 1 - par],
                               sx[i0c - n0 + 10 + par - t], acc);
                yv[q] = 2.0f * acc;
            }
        }
    }

    // ---- Phase 4: snake activation y += sin(a*y)^2 / (a+eps) ----
#pragma unroll
    for (int q = 0; q < 26; ++q) {
        const float s = __sinf(a * yv[q]);
        yv[q] = fmaf(s * s, inv_a, yv[q]);
    }

    // ---- Phase 5: downsample out[N+r] = sum_k wdn[k] * yv[2r+k] ----
    float o[OPT];
#pragma unroll
    for (int r = 0; r < OPT; ++r) {
        float acc = 0.0f;
#pragma unroll
        for (int k = 0; k < 12; ++k)
            acc = fmaf(wdn[k], yv[2 * r + k], acc);
        o[r] = acc;
    }

    *reinterpret_cast<float4*>(orow + N)     = make_float4(o[0], o[1], o[2], o[3]);
    *reinterpret_cast<float4*>(orow + N + 4) = make_float4(o[4], o[5], o[6], o[7]);
}

extern "C" void kernel_launch(void* const* d_in, const int* in_sizes, int n_in,
                              void* d_out, int out_size, void* d_ws, size_t ws_size,
                              hipStream_t stream)
{
    const float* x     = (const float*)d_in[0];
    const float* alpha = (const float*)d_in[1];
    const float* wup   = (const float*)d_in[2];
    const float* wdn   = (const float*)d_in[3];
    float*       out   = (float*)d_out;

    const int B_N  = out_size / (C_N * T_LEN);  // 8
    const int grid = B_N * C_N * NCHUNK;        // 16384

    act1d_fused<<<grid, BLOCK, 0, stream>>>(x, alpha, wup, wdn, out);
}

// Round 2
// 56.143 us; speedup vs baseline: 1.3755x; 1.3755x over previous
//
#include <hip/hip_runtime.h>

// B=8, C=512, T=8192, RATIO=2, K=12
#define T_LEN 8192
#define C_N   512
#define BLOCK 256
#define NCHUNK 4
#define INV_2PI 0.15915494309189535f

// Verified formulas (ground truth = round-0 passing kernel):
//   y[2i]   = 2 * sum_t wup[2t+1] * xc[i+2-t]   (t=0..5, xc = edge-clamped x)
//   y[2i+1] = 2 * sum_t wup[2t]   * xc[i+3-t]
//   snake:   y += sin(a*y)^2 / (a+1e-9)
//   out[n]  = sum_k wdn[k] * ypad[2n-5+k]       (ypad = edge-clamped y)
//
// Mapping: lane handles outputs N..N+7, N = chunk*2048 + 8*tid.
//   own pairs i = N-3..N+4  -> yv[u] = y[2N-6+u], u=0..15
//   halo h[v] = y[2N+10+v], v=0..10  <- lane+1's yv[0..10] via shfl_down
//   lane 63 computes h itself (needs x[N+8..N+13] extra loads)
//   Y[j] = y[2N-5+j] = (j<15 ? yv[j+1] : h[j-15]),  out[N+r]=sum_k wdn[k]*Y[2r+k]

__global__ __launch_bounds__(BLOCK) void act1d_fused(
    const float* __restrict__ x,
    const float* __restrict__ alpha,
    const float* __restrict__ wup_g,
    const float* __restrict__ wdn_g,
    float* __restrict__ out)
{
    const int bx    = blockIdx.x;
    const int chunk = bx & (NCHUNK - 1);
    const int bc    = bx >> 2;
    const int c     = bc & (C_N - 1);
    const int tid   = threadIdx.x;
    const int lane  = tid & 63;
    const int N     = chunk * 2048 + 8 * tid;   // first output of this lane

    const float* __restrict__ xrow = x   + (size_t)bc * T_LEN;
    float*       __restrict__ orow = out + (size_t)bc * T_LEN;

    // ---- uniform constants (scalar loads) ----
    float u2[12], wdn[12];
#pragma unroll
    for (int i = 0; i < 12; ++i) {
        u2[i]  = wup_g[i] + wup_g[i];   // fold the *2 of the transposed conv
        wdn[i] = wdn_g[i];
    }
    const float a     = __expf(alpha[c]);
    const float inv_a = 1.0f / (a + 1e-9f);
    const float ka    = a * INV_2PI;    // v_sin_f32 takes revolutions

    // ---- x window: xr[u] = xc[N-8+u], u=0..15 ----
    float xr[16];
    if (N >= 8) {
        const float4 A = *reinterpret_cast<const float4*>(xrow + N - 8);
        const float4 Bv = *reinterpret_cast<const float4*>(xrow + N - 4);
        const float4 Cv = *reinterpret_cast<const float4*>(xrow + N);
        const float4 Dv = *reinterpret_cast<const float4*>(xrow + N + 4);
        xr[0]=A.x; xr[1]=A.y; xr[2]=A.z; xr[3]=A.w;
        xr[4]=Bv.x; xr[5]=Bv.y; xr[6]=Bv.z; xr[7]=Bv.w;
        xr[8]=Cv.x; xr[9]=Cv.y; xr[10]=Cv.z; xr[11]=Cv.w;
        xr[12]=Dv.x; xr[13]=Dv.y; xr[14]=Dv.z; xr[15]=Dv.w;
    } else {   // only N==0: left edge clamp
#pragma unroll
        for (int u = 0; u < 16; ++u)
            xr[u] = xrow[max(N - 8 + u, 0)];
    }

    // ---- own 8 pairs: upsample + snake, all in registers ----
    float yv[16];
#pragma unroll
    for (int p = 0; p < 8; ++p) {
        float ae = 0.0f, ao = 0.0f;
#pragma unroll
        for (int t = 0; t < 6; ++t) {
            ae = fmaf(u2[2 * t + 1], xr[7 + p - t], ae);   // y[2(N-3+p)]
            ao = fmaf(u2[2 * t],     xr[8 + p - t], ao);   // y[2(N-3+p)+1]
        }
        yv[2 * p]     = ae;
        yv[2 * p + 1] = ao;
    }
#pragma unroll
    for (int q = 0; q < 16; ++q) {
        const float s = __builtin_amdgcn_sinf(ka * yv[q]);  // sin(a*y)
        yv[q] = fmaf(s * s, inv_a, yv[q]);
    }

    // ---- left edge: ypad[m<0] = y[0] (= yv[6] when N==0) ----
    if (N == 0) {
        yv[1] = yv[2] = yv[3] = yv[4] = yv[5] = yv[6];
    }

    // ---- halo from lane+1 ----
    float h[11];
#pragma unroll
    for (int v = 0; v < 11; ++v)
        h[v] = __shfl_down(yv[v], 1, 64);

    // ---- lane 63: compute halo itself (pairs i = N+5..N+10) ----
    if (lane == 63) {
        float xh[6];   // xh[u] = xc[N+8+u], u=0..5
        if (N + 13 < T_LEN) {
            const float4 A = *reinterpret_cast<const float4*>(xrow + N + 8);
            const float4 Bv = *reinterpret_cast<const float4*>(xrow + N + 12);
            xh[0]=A.x; xh[1]=A.y; xh[2]=A.z; xh[3]=A.w; xh[4]=Bv.x; xh[5]=Bv.y;
        } else {
#pragma unroll
            for (int u = 0; u < 6; ++u)
                xh[u] = xrow[min(N + 8 + u, T_LEN - 1)];
        }
        // xx[u] = xc[N-8+u]: u<16 -> xr, else xh[u-16]  (u is compile-time)
#define XX(u) ((u) < 16 ? xr[(u) < 16 ? (u) : 0] : xh[(u) >= 16 ? (u) - 16 : 0])
#pragma unroll
        for (int pp = 0; pp < 6; ++pp) {
            // even: h[2pp] = y[2(N+5+pp)], taps xx[15+pp-t]
            float ae = 0.0f;
#pragma unroll
            for (int t = 0; t < 6; ++t)
                ae = fmaf(u2[2 * t + 1], XX(15 + pp - t), ae);
            {
                const float s = __builtin_amdgcn_sinf(ka * ae);
                ae = fmaf(s * s, inv_a, ae);
            }
            h[2 * pp] = ae;
            if (pp < 5) {
                // odd: h[2pp+1] = y[2(N+5+pp)+1], taps xx[16+pp-t]
                float ao = 0.0f;
#pragma unroll
                for (int t = 0; t < 6; ++t)
                    ao = fmaf(u2[2 * t], XX(16 + pp - t), ao);
                const float s = __builtin_amdgcn_sinf(ka * ao);
                ao = fmaf(s * s, inv_a, ao);
                h[2 * pp + 1] = ao;
            }
        }
#undef XX
    }

    // ---- right edge: ypad[m>16383] = y[16383] (= h[5] when N==T-8) ----
    if (N == T_LEN - 8) {
        h[6] = h[7] = h[8] = h[9] = h[10] = h[5];
    }

    // ---- downsample: out[N+r] = sum_k wdn[k] * Y[2r+k] ----
    float o[8];
#pragma unroll
    for (int r = 0; r < 8; ++r) {
        float acc = 0.0f;
#pragma unroll
        for (int k = 0; k < 12; ++k) {
            const int j = 2 * r + k;
            acc = fmaf(wdn[k], (j < 15 ? yv[j + 1] : h[j - 15]), acc);
        }
        o[r] = acc;
    }

    *reinterpret_cast<float4*>(orow + N)     = make_float4(o[0], o[1], o[2], o[3]);
    *reinterpret_cast<float4*>(orow + N + 4) = make_float4(o[4], o[5], o[6], o[7]);
}

extern "C" void kernel_launch(void* const* d_in, const int* in_sizes, int n_in,
                              void* d_out, int out_size, void* d_ws, size_t ws_size,
                              hipStream_t stream)
{
    const float* x     = (const float*)d_in[0];
    const float* alpha = (const float*)d_in[1];
    const float* wup   = (const float*)d_in[2];
    const float* wdn   = (const float*)d_in[3];
    float*       out   = (float*)d_out;

    const int B_N  = out_size / (C_N * T_LEN);   // 8
    const int grid = B_N * C_N * NCHUNK;         // 16384

    act1d_fused<<<grid, BLOCK, 0, stream>>>(x, alpha, wup, wdn, out);
}